// Round 13
// baseline (617.370 us; speedup 1.0000x reference)
//
#include <hip/hip_runtime.h>

#define TT  512
#define HD  18
#define NB  16
#define NTH 128          /* 2 waves: w0 = layer 1, w1 = layer 2 */

typedef _Float16 v8h __attribute__((ext_vector_type(8)));
typedef float    v4f __attribute__((ext_vector_type(4)));

__device__ __forceinline__ float fsig(float x) {
    return __builtin_amdgcn_rcpf(1.0f + __expf(-x));
}

__device__ __forceinline__ uint pack2(float lo, float hi) {
    union { _Float16 h[2]; uint u; } cv;
    cv.h[0] = (_Float16)lo; cv.h[1] = (_Float16)hi;
    return cv.u;
}

__device__ __forceinline__ uint sel4(int lg, uint a, uint b, uint c, uint d) {
    return lg == 0 ? a : (lg == 1 ? b : (lg == 2 ? c : d));
}

// validated soft barrier (R10): LDS drain + HW barrier + compiler memory fence
__device__ __forceinline__ void softbar() {
    asm volatile("s_waitcnt lgkmcnt(0)" ::: "memory");
    __builtin_amdgcn_s_barrier();
    asm volatile("" ::: "memory");
}

__global__ __launch_bounds__(NTH) void lstm2_wavepipe(
    const float* __restrict__ x,
    const float* __restrict__ wih0, const float* __restrict__ whh0,
    const float* __restrict__ bih0, const float* __restrict__ bhh0,
    const float* __restrict__ wih1, const float* __restrict__ whh1,
    const float* __restrict__ bih1, const float* __restrict__ bhh1,
    float* __restrict__ out)
{
    // ring: x[t] rows (16 dwords/row: d0-8 = 9 f16-pairs, d9-15 = 0)
    // h1s : h1 double buffer, same row format
    __shared__ __align__(16) uint ring[4][NB][16];
    __shared__ __align__(16) uint h1s[2][NB][16];

    const int tid  = threadIdx.x;
    const int wid  = tid >> 6;      // 0: layer-1 wave, 1: layer-2 wave
    const int lane = tid & 63;
    const int rl   = lane & 15;     // batch column
    const int lg   = lane >> 4;     // k-group / h-subrow
    const int pp   = lg >> 1;       // pair parity
    const size_t b0 = (size_t)blockIdx.x * NB;

    // ---- zero LDS ----
    for (int i = tid; i < 4 * NB * 16; i += NTH) ((uint*)ring)[i] = 0u;
    for (int i = tid; i < 2 * NB * 16; i += NTH) ((uint*)h1s)[i]  = 0u;

    // ---- per-wave layer params ----
    const float* wih = wid ? wih1 : wih0;
    const float* whh = wid ? whh1 : whh0;
    const float* bi  = wid ? bih1 : bih0;
    const float* bh  = wid ? bhh1 : bhh0;

    // ---- A fragments (row = 4h+g permutation) + acc-init biases ----
    v8h A1[5], A2[5];
    v4f bias[5];
    #pragma unroll
    for (int t = 0; t < 5; ++t) {
        const int row = 16 * t + rl;
        const int h = row >> 2, g = row & 3;
        const int r = g * HD + h;
        v8h a1, a2;
        #pragma unroll
        for (int j = 0; j < 8; ++j) {
            const int k = 8 * lg + j;
            float w1v = 0.f, w2v = 0.f;
            if (h < HD && k < HD) { w1v = wih[r * HD + k]; w2v = whh[r * HD + k]; }
            a1[j] = (_Float16)w1v; a2[j] = (_Float16)w2v;
        }
        A1[t] = a1; A2[t] = a2;
        const int hc = 4 * t + lg;          // this lane's h for tile t (C layout)
        v4f bv;
        #pragma unroll
        for (int g2 = 0; g2 < 4; ++g2)
            bv[g2] = (hc < HD) ? (bi[g2 * HD + hc] + bh[g2 * HD + hc]) : 0.f;
        bias[t] = bv;
    }

    // ---- x staging: 144 f16-pairs over 128 lanes -> up to 2 pairs per lane ----
    // set 0: pidx = wid*64+lane (0..127); set 1: pidx+128 (w0 lanes 0..15)
    const int  pidx0 = wid * 64 + lane;
    const int  pidx1 = pidx0 + 128;
    const bool pv0   = pidx0 < NB * 9;          // always true, kept for clarity
    const bool pv1   = pidx1 < NB * 9;          // w0 lanes 0..15
    const int  pb0 = pidx0 / 9, pm0 = pidx0 % 9;
    const int  pb1 = pv1 ? pidx1 / 9 : 0, pm1 = pv1 ? pidx1 % 9 : 0;
    const float* xpp0 = x + (b0 + pb0) * (size_t)TT * HD + 2 * pm0;
    const float* xpp1 = x + (b0 + pb1) * (size_t)TT * HD + 2 * pm1;

    __syncthreads();                         // zeros visible before preload
    #pragma unroll
    for (int t = 0; t < 3; ++t) {
        if (pv0) {
            const float2 v = *(const float2*)(xpp0 + t * HD);
            ring[t][pb0][pm0] = pack2(v.x, v.y);
        }
        if (pv1) {
            const float2 v = *(const float2*)(xpp1 + t * HD);
            ring[t][pb1][pm1] = pack2(v.x, v.y);
        }
    }
    float2 xh0 = make_float2(0.f, 0.f), xh1 = make_float2(0.f, 0.f);
    if (pv0) xh0 = *(const float2*)(xpp0 + 3 * HD);   // x[3], written at slot 0
    if (pv1) xh1 = *(const float2*)(xpp1 + 3 * HD);
    __syncthreads();

    float cst[5] = {0.f, 0.f, 0.f, 0.f, 0.f};
    uint B2d0 = 0, B2d1 = 0, B2d2 = 0, B2d3 = 0;     // own-h B frag (h[-1]=0)
    float* op = out + (b0 + rl) * (size_t)TT * HD;

    for (int n = 0; n <= TT; ++n) {
        const bool active = (wid == 0) ? (n < TT) : (n >= 1);
        if (active) {
            // input-part B fragment: x[n] (w0) or h1[n-1] (w1), b128 broadcast
            const uint* rowp = (wid == 0) ? &ring[n & 3][rl][0]
                                          : &h1s[(n - 1) & 1][rl][0];
            union { uint4 q; v8h v; } ub1;
            ub1.q = *(const uint4*)(rowp + 4 * lg);
            const v8h Bf1 = ub1.v;
            union { uint u[4]; v8h v; } ub2;
            ub2.u[0] = B2d0; ub2.u[1] = B2d1; ub2.u[2] = B2d2; ub2.u[3] = B2d3;
            const v8h Bf2 = ub2.v;

            float hv[5];
            #pragma unroll
            for (int t = 0; t < 5; ++t) {
                v4f acc = bias[t];
                acc = __builtin_amdgcn_mfma_f32_16x16x32_f16(A1[t], Bf1, acc, 0, 0, 0);
                acc = __builtin_amdgcn_mfma_f32_16x16x32_f16(A2[t], Bf2, acc, 0, 0, 0);
                const float gi = fsig(acc[0]);
                const float gf = fsig(acc[1]);
                const float gg = 2.f * fsig(2.f * acc[2]) - 1.f;
                const float go = fsig(acc[3]);
                cst[t] = gf * cst[t] + gi * gg;
                const float th = 2.f * fsig(2.f * cst[t]) - 1.f;
                hv[t] = go * th;
            }

            // ---- replicate h across the wave: 2 shuffles + pack per tile ----
            uint pk0[5], pk1[5];
            #pragma unroll
            for (int t = 0; t < 5; ++t) {
                const float a = hv[t];
                const float b = __shfl_xor(a, 16, 64);          // partner lg^1
                const float lo = ((lg & 1) == 0) ? a : b;
                const float hi = ((lg & 1) == 0) ? b : a;
                const uint  pe = pack2(lo, hi);                 // pair (h[4t+2pp], h[4t+2pp+1])
                const uint  po = (uint)__shfl_xor((int)pe, 32, 64);  // pair pp^1
                pk0[t] = (pp == 0) ? pe : po;                   // (h[4t],   h[4t+1])
                pk1[t] = (pp == 0) ? po : pe;                   // (h[4t+2], h[4t+3])
            }
            // next-step own-h B fragment: lane lg needs h[8lg .. 8lg+7]
            B2d0 = sel4(lg, pk0[0], pk0[2], pk0[4], 0u);
            B2d1 = sel4(lg, pk1[0], pk1[2], 0u,     0u);
            B2d2 = sel4(lg, pk0[1], pk0[3], 0u,     0u);
            B2d3 = sel4(lg, pk1[1], pk1[3], 0u,     0u);

            if (wid == 0) {
                // publish h1[n] for the layer-2 wave (every lane has full pk)
                uint* hrow = &h1s[n & 1][rl][0];
                if (lg == 0) {
                    uint4 w; w.x = pk0[0]; w.y = pk1[0]; w.z = pk0[1]; w.w = pk1[1];
                    *(uint4*)(hrow + 0) = w;
                } else if (lg == 1) {
                    uint4 w; w.x = pk0[2]; w.y = pk1[2]; w.z = pk0[3]; w.w = pk1[3];
                    *(uint4*)(hrow + 4) = w;
                } else if (lg == 2) {
                    hrow[8] = pk0[4];
                }
            } else {
                const int m = n - 1;                 // h2[m] just computed
                #pragma unroll
                for (int t = 0; t < 5; ++t) {
                    const int hc = 4 * t + lg;
                    if (hc < HD) op[(size_t)m * HD + hc] = hv[t];
                }
            }
        }

        // ---- x staging: write x[n+3] (held 1 slot), issue load of x[n+4] ----
        if (n + 3 < TT) {
            const int xb = (n + 3) & 3;
            if (pv0) ring[xb][pb0][pm0] = pack2(xh0.x, xh0.y);
            if (pv1) ring[xb][pb1][pm1] = pack2(xh1.x, xh1.y);
        }
        if (n + 4 < TT) {
            if (pv0) xh0 = *(const float2*)(xpp0 + (size_t)(n + 4) * HD);
            if (pv1) xh1 = *(const float2*)(xpp1 + (size_t)(n + 4) * HD);
        }

        softbar();
    }
}

extern "C" void kernel_launch(void* const* d_in, const int* in_sizes, int n_in,
                              void* d_out, int out_size, void* d_ws, size_t ws_size,
                              hipStream_t stream) {
    const float* x    = (const float*)d_in[0];
    const float* wih0 = (const float*)d_in[1];
    const float* whh0 = (const float*)d_in[2];
    const float* bih0 = (const float*)d_in[3];
    const float* bhh0 = (const float*)d_in[4];
    const float* wih1 = (const float*)d_in[5];
    const float* whh1 = (const float*)d_in[6];
    const float* bih1 = (const float*)d_in[7];
    const float* bhh1 = (const float*)d_in[8];
    float* out = (float*)d_out;
    (void)d_ws; (void)ws_size; (void)in_sizes; (void)n_in; (void)out_size;

    lstm2_wavepipe<<<dim3(4096 / NB), dim3(NTH), 0, stream>>>(
        x, wih0, whh0, bih0, bhh0, wih1, whh1, bih1, bhh1, out);
}

// Round 14
// 519.068 us; speedup vs baseline: 1.1894x; 1.1894x over previous
//
#include <hip/hip_runtime.h>

#define TT  512
#define HD  18
#define NB  16
#define NTH 128          /* 2 waves: w0 = layer 1, w1 = layer 2 */
#define RS  40           /* halves per row (80B): [in(18)|h(18)|pad(4)] */

typedef _Float16 v8h __attribute__((ext_vector_type(8)));
typedef float    v4f __attribute__((ext_vector_type(4)));

__device__ __forceinline__ float fsig(float x) {
    return __builtin_amdgcn_rcpf(1.0f + __expf(-x));
}
__device__ __forceinline__ uint pack2(float lo, float hi) {
    union { _Float16 h[2]; uint u; } cv;
    cv.h[0] = (_Float16)lo; cv.h[1] = (_Float16)hi;
    return cv.u;
}
// validated soft barrier (R10): LDS drain + HW barrier + compiler memory fence
__device__ __forceinline__ void softbar() {
    asm volatile("s_waitcnt lgkmcnt(0)" ::: "memory");
    __builtin_amdgcn_s_barrier();
    asm volatile("" ::: "memory");
}

__global__ __launch_bounds__(NTH) void lstm2_layerwave(
    const float* __restrict__ x,
    const float* __restrict__ wih0, const float* __restrict__ whh0,
    const float* __restrict__ bih0, const float* __restrict__ bhh0,
    const float* __restrict__ wih1, const float* __restrict__ whh1,
    const float* __restrict__ bih1, const float* __restrict__ bhh1,
    float* __restrict__ out)
{
    // ring[s] rows: [x[t](18) | h1[t-1](18) | pad]; l2b[p]: [h1(18) | h2(18) | pad]
    // 17 rows: row 16 is a ghost row absorbing the s1 over-read of rl=15.
    __shared__ __align__(16) _Float16 ring[4][17][RS];
    __shared__ __align__(16) _Float16 l2b [2][17][RS];

    const int tid  = threadIdx.x;
    const int wid  = tid >> 6;      // 0: layer-1 wave, 1: layer-2 wave
    const int lane = tid & 63;
    const int rl   = lane & 15;     // batch column
    const int lg   = lane >> 4;     // k-group / h-subrow
    const size_t b0 = (size_t)blockIdx.x * NB;

    // ---- zero all LDS (incl. ghost rows and pads) ----
    {
        uint* rz = (uint*)&ring[0][0][0];
        for (int i = tid; i < 4 * 17 * RS / 2; i += NTH) rz[i] = 0u;
        uint* lz = (uint*)&l2b[0][0][0];
        for (int i = tid; i < 2 * 17 * RS / 2; i += NTH) lz[i] = 0u;
    }

    // ---- per-wave layer params ----
    const float* wih = wid ? wih1 : wih0;
    const float* whh = wid ? whh1 : whh0;
    const float* bi  = wid ? bih1 : bih0;
    const float* bh  = wid ? bhh1 : bhh0;

    // ---- A fragments + acc-init biases ----
    // k-map s0: k=8lg+j, k<18 -> wih, 18<=k<32 -> whh[.. k-18] (h-units 0..13)
    // k-map s1: lg==0, j<4 -> whh[.. 14+j]; all else 0 (B s1 garbage-tolerant)
    v8h A1[5], A2[5];
    v4f bias[5];
    #pragma unroll
    for (int t = 0; t < 5; ++t) {
        const int row = 16 * t + rl;
        const int h = row >> 2, g = row & 3;
        const int r = g * HD + h;
        v8h a1, a2;
        #pragma unroll
        for (int j = 0; j < 8; ++j) {
            const int k = 8 * lg + j;
            float v1 = 0.f, v2 = 0.f;
            if (h < HD) {
                if (k < HD)            v1 = wih[r * HD + k];
                else if (k < 2 * HD - 4) v1 = whh[r * HD + (k - HD)];   // k-18 in 0..13
                if (lg == 0 && j < 4)  v2 = whh[r * HD + 14 + j];       // k=32..35
            }
            a1[j] = (_Float16)v1;
            a2[j] = (_Float16)v2;
        }
        A1[t] = a1; A2[t] = a2;
        const int hc = 4 * t + lg;
        v4f bv;
        #pragma unroll
        for (int g2 = 0; g2 < 4; ++g2)
            bv[g2] = (hc < HD) ? (bi[g2 * HD + hc] + bh[g2 * HD + hc]) : 0.f;
        bias[t] = bv;
    }

    // ---- x staging duty (w1): 144 pairs = 64 + 64 + 16 ----
    const int p0 = lane, p1 = lane + 64, p2 = lane + 128;
    const bool v2ok = (lane < 16);
    const int pb0 = p0 / 9, pm0 = p0 % 9;
    const int pb1 = p1 / 9, pm1 = p1 % 9;
    const int pb2 = v2ok ? p2 / 9 : 0, pm2 = v2ok ? p2 % 9 : 0;
    const float* xq0 = x + (b0 + pb0) * (size_t)TT * HD + 2 * pm0;
    const float* xq1 = x + (b0 + pb1) * (size_t)TT * HD + 2 * pm1;
    const float* xq2 = x + (b0 + pb2) * (size_t)TT * HD + 2 * pm2;

    __syncthreads();   // zeros visible

    // ---- preload x[0..2] into ring slots 0..2 (all 128 threads, 144 pairs) ----
    #pragma unroll
    for (int s = 0; s < 3; ++s) {
        {
            const int p = tid, pb = p / 9, pm = p % 9;   // p < 128 < 144
            const float2 v = *(const float2*)(x + (b0 + pb) * (size_t)TT * HD + s * HD + 2 * pm);
            ((uint*)&ring[s][pb][0])[pm] = pack2(v.x, v.y);
        }
        if (tid < 16) {
            const int p = tid + 128, pb = p / 9, pm = p % 9;
            const float2 v = *(const float2*)(x + (b0 + pb) * (size_t)TT * HD + s * HD + 2 * pm);
            ((uint*)&ring[s][pb][0])[pm] = pack2(v.x, v.y);
        }
    }
    // w1 holds x[3] pairs in registers (written to ring[3] at step 0)
    float2 xh0 = make_float2(0.f, 0.f), xh1 = xh0, xh2 = xh0;
    if (wid == 1) {
        xh0 = *(const float2*)(xq0 + 3 * HD);
        xh1 = *(const float2*)(xq1 + 3 * HD);
        if (v2ok) xh2 = *(const float2*)(xq2 + 3 * HD);
    }
    __syncthreads();

    float cst[5] = {0.f, 0.f, 0.f, 0.f, 0.f};
    float* op = out + (b0 + rl) * (size_t)TT * HD;

    for (int n = 0; n <= TT; ++n) {
        const bool act = wid ? (n >= 1) : (n < TT);

        // ---- read B for this step (one read pair serves all 5 tiles) ----
        v8h B0{}, B1{};
        if (act) {
            const _Float16* rowp = wid ? &l2b[n & 1][rl][0] : &ring[n & 3][rl][0];
            B0 = *(const v8h*)(rowp + 8 * lg);        // k 0..31
            B1 = *(const v8h*)(rowp + 32 + 8 * lg);   // k 32..35 (+garbage, A2=0)
        }

        // ---- issue next x loads (w1) while B-read latency drains ----
        float2 xn0 = xh0, xn1 = xh1, xn2 = xh2;
        if (wid == 1 && (n + 4) < TT) {
            xn0 = *(const float2*)(xq0 + (size_t)(n + 4) * HD);
            xn1 = *(const float2*)(xq1 + (size_t)(n + 4) * HD);
            if (v2ok) xn2 = *(const float2*)(xq2 + (size_t)(n + 4) * HD);
        }

        if (act) {
            float hv[5];
            #pragma unroll
            for (int t = 0; t < 5; ++t) {
                v4f acc = __builtin_amdgcn_mfma_f32_16x16x32_f16(A1[t], B0, bias[t], 0, 0, 0);
                acc = __builtin_amdgcn_mfma_f32_16x16x32_f16(A2[t], B1, acc, 0, 0, 0);
                const float gi = fsig(acc[0]);
                const float gf = fsig(acc[1]);
                const float gg = 2.f * fsig(2.f * acc[2]) - 1.f;   // tanh
                const float go = fsig(acc[3]);
                cst[t] = gf * cst[t] + gi * gg;
                const float th = 2.f * fsig(2.f * cst[t]) - 1.f;
                hv[t] = go * th;
            }
            // ---- write h: own recurrence (same wave) + cross handoff ----
            #pragma unroll
            for (int t = 0; t < 5; ++t) {
                const int hc = 4 * t + lg;
                if (hc < HD) {
                    const _Float16 h16 = (_Float16)hv[t];
                    if (wid == 0) {
                        ring[(n + 1) & 3][rl][HD + hc] = h16;   // own next input
                        l2b [(n + 1) & 1][rl][hc]      = h16;   // h1 -> layer 2
                    } else {
                        l2b [(n + 1) & 1][rl][HD + hc] = h16;   // own next input
                        op[(size_t)(n - 1) * HD + hc] = hv[t];  // final output
                    }
                }
            }
        }

        // ---- x ring maintenance (w1): write x[n+3] (held), rotate ----
        if (wid == 1) {
            if ((n + 3) < TT) {
                const int s = (n + 3) & 3;
                ((uint*)&ring[s][pb0][0])[pm0] = pack2(xh0.x, xh0.y);
                ((uint*)&ring[s][pb1][0])[pm1] = pack2(xh1.x, xh1.y);
                if (v2ok) ((uint*)&ring[s][pb2][0])[pm2] = pack2(xh2.x, xh2.y);
            }
            xh0 = xn0; xh1 = xn1; xh2 = xn2;
        }

        softbar();
    }
}

extern "C" void kernel_launch(void* const* d_in, const int* in_sizes, int n_in,
                              void* d_out, int out_size, void* d_ws, size_t ws_size,
                              hipStream_t stream) {
    const float* x    = (const float*)d_in[0];
    const float* wih0 = (const float*)d_in[1];
    const float* whh0 = (const float*)d_in[2];
    const float* bih0 = (const float*)d_in[3];
    const float* bhh0 = (const float*)d_in[4];
    const float* wih1 = (const float*)d_in[5];
    const float* whh1 = (const float*)d_in[6];
    const float* bih1 = (const float*)d_in[7];
    const float* bhh1 = (const float*)d_in[8];
    float* out = (float*)d_out;
    (void)d_ws; (void)ws_size; (void)in_sizes; (void)n_in; (void)out_size;

    lstm2_layerwave<<<dim3(4096 / NB), dim3(NTH), 0, stream>>>(
        x, wih0, whh0, bih0, bhh0, wih1, whh1, bih1, bhh1, out);
}